// Round 16
// baseline (106.569 us; speedup 1.0000x reference)
//
#include <hip/hip_runtime.h>
#include <hip/hip_bf16.h>
#include <stdint.h>

// C[4096,10532] = inputs[4096,256] @ concat(lut,queue)[10532,256]^T  (fp32 out)
// R16: ZERO-LDS ZERO-BARRIER persistent-breg kernel. R15 confirmed the LDS
// phase was serial with the store drain (43.5us = 21 x (0.76 compute + 1.31
// store)); the per-subtile s_barrier locked all 8 waves into lockstep phases
// so HBM writes idled during compute. Now: B in regs (as R15), A fragments
// streamed DIRECTLY global->VGPR (8x redundant per CU but L2-hot: 0.4us/CU/
// subtile), no barriers at all -> waves free-run and stores overlap compute
// across waves. unroll-2 lets the compiler pipeline next-subtile loads under
// current MFMAs. VGPR ~180 (breg 64 + a 64 + acc 16) at (512,1).

#define M_DIM 4096
#define K_DIM 256
#define N_LUT 5532
#define N_Q   5000
#define N_DIM (N_LUT + N_Q)   // 10532
#define BN    256
#define NT_N  42              // ceil(10532/256)
#define N_PAD (NT_N * 256)    // 10752
#define NSTRIP 6              // m-strips; 128 subtiles of 32 rows split 21/22

typedef _Float16 f16x8 __attribute__((ext_vector_type(8)));
typedef float f32x4 __attribute__((ext_vector_type(4)));

__device__ __forceinline__ unsigned short f2h(float f) {
  union { _Float16 h; unsigned short u; } v;
  v.h = (_Float16)f;   // v_cvt_f16_f32, RNE
  return v.u;
}

// ---------------- convert fp32 -> f16 into workspace ----------------
__global__ __launch_bounds__(256) void convert_kernel(
    const float* __restrict__ inp, const float* __restrict__ lut,
    const float* __restrict__ que, unsigned short* __restrict__ Abf,
    unsigned short* __restrict__ Bbf) {
  const int AV = M_DIM * K_DIM / 4;  // 262144 float4s for A
  int i = blockIdx.x * 256 + threadIdx.x;  // grid sized exactly
  float4 x;
  unsigned short* dst;
  if (i < AV) {
    x = ((const float4*)inp)[i];
    dst = Abf + i * 4;
  } else {
    int e = (i - AV) * 4;          // element index in padded B
    int row = e >> 8;              // /256
    int col = e & 255;
    if (row < N_LUT)
      x = *(const float4*)(lut + (size_t)row * K_DIM + col);
    else if (row < N_DIM)
      x = *(const float4*)(que + (size_t)(row - N_LUT) * K_DIM + col);
    else
      x = make_float4(0.f, 0.f, 0.f, 0.f);
    dst = Bbf + e;
  }
  ushort4 o;
  o.x = f2h(x.x); o.y = f2h(x.y); o.z = f2h(x.z); o.w = f2h(x.w);
  *(ushort4*)dst = o;
}

// -------- GEMM: persistent-B-in-regs, direct-global streaming-A ----------
__global__ __launch_bounds__(512, 1) void gemm_kernel(
    const unsigned short* __restrict__ A, const unsigned short* __restrict__ B,
    float* __restrict__ C) {
  const int t = threadIdx.x;
  const int lane = t & 63;
  const int wave = t >> 6;         // 8 waves; wave w owns C-cols w*32..+32

  const int bid = blockIdx.x;      // 252 blocks: bn fast, strip slow
  const int bn = bid % NT_N;
  const int s = bid / NT_N;        // strip 0..5
  const int bcol = bn * BN;
  // strips: subtile counts 21,21,21,21,22,22 (sum 128)
  const int csub = 21 + (s >= 4 ? 1 : 0);
  const int sub0 = 21 * s + (s >= 5 ? 1 : 0);   // s=5 starts at 106
  const int row0 = sub0 * 32;

  const int lr = lane & 15;
  const int cq = lane >> 4;        // 0..3
  const int cc4 = cq * 4;

  // ---- persistent B fragments -> registers (64 VGPR) ----
  // breg[j][ks]: B-row = bcol + wave*32 + j*16 + lr, k = ks*32 + cq*8.
  // Bbf padded/zeroed to N_PAD rows -> bn==41 loads in-bounds.
  f16x8 breg[2][8];
#pragma unroll
  for (int j = 0; j < 2; ++j) {
    const unsigned short* brow =
        B + (size_t)(bcol + wave * 32 + j * 16 + lr) * K_DIM + cq * 8;
#pragma unroll
    for (int ks = 0; ks < 8; ++ks)
      breg[j][ks] = *(const f16x8*)(brow + ks * 32);
  }

  // per-lane A base: row = row0 + lr (+ i*16 + sub*32), k-slice = cq*8 (+ks*32)
  const unsigned short* aBase = A + (size_t)(row0 + lr) * K_DIM + cq * 8;

#pragma unroll 2
  for (int sub = 0; sub < csub; ++sub) {
    const unsigned short* ap = aBase + (size_t)sub * 32 * K_DIM;
    // 16 a-fragment loads (64B-sector coalesced: 4 cq-lanes x 16B per row);
    // all independent of the stores below -> compiler pipelines across iters
    f16x8 a[2][8];
#pragma unroll
    for (int i = 0; i < 2; ++i)
#pragma unroll
      for (int ks = 0; ks < 8; ++ks)
        a[i][ks] = *(const f16x8*)(ap + i * 16 * K_DIM + ks * 32);

    f32x4 acc[2][2] = {};
#pragma unroll
    for (int ks = 0; ks < 8; ++ks)         // K = 256 = 8 x 32
#pragma unroll
      for (int i = 0; i < 2; ++i)
#pragma unroll
        for (int j = 0; j < 2; ++j)
          // swapped operands: C-row = i*16+lr, C-cols = j*16 + cc4 + reg
          acc[i][j] = __builtin_amdgcn_mfma_f32_16x16x32_f16(
              breg[j][ks], a[i][ks], acc[i][j], 0, 0, 0);

    // 4 dwordx4 C-stores; no barrier anywhere -> drain under other waves'
    // compute (waves fully decoupled)
#pragma unroll
    for (int i = 0; i < 2; ++i) {
      size_t rowBase = (size_t)(row0 + sub * 32 + i * 16 + lr) * N_DIM;
#pragma unroll
      for (int j = 0; j < 2; ++j) {
        int col = bcol + wave * 32 + j * 16 + cc4;
        if (col < N_DIM)           // N_DIM%4==0: granule fully valid
          *(f32x4*)&C[rowBase + col] = acc[i][j];
      }
    }
  }
}

extern "C" void kernel_launch(void* const* d_in, const int* in_sizes, int n_in,
                              void* d_out, int out_size, void* d_ws, size_t ws_size,
                              hipStream_t stream) {
  const float* inp = (const float*)d_in[0];   // inputs [4096,256]
  // d_in[1] targets, d_in[2] gt_flag: unused by the forward similarity
  const float* lut = (const float*)d_in[3];   // [5532,256]
  const float* que = (const float*)d_in[4];   // [5000,256]
  float* C = (float*)d_out;                   // [4096,10532]

  unsigned short* Abf = (unsigned short*)d_ws;
  unsigned short* Bbf = Abf + (size_t)M_DIM * K_DIM;  // ~7.7 MB of ws

  const int conv_blocks = (M_DIM * K_DIM / 4 + N_PAD * K_DIM / 4) / 256;
  convert_kernel<<<conv_blocks, 256, 0, stream>>>(inp, lut, que, Abf, Bbf);

  gemm_kernel<<<NSTRIP * NT_N, 512, 0, stream>>>(Abf, Bbf, C);
}

// Round 17
// 51.008 us; speedup vs baseline: 2.0893x; 2.0893x over previous
//
#include <hip/hip_runtime.h>
#include <hip/hip_bf16.h>
#include <stdint.h>

// C[4096,10532] = inputs[4096,256] @ concat(lut,queue)[10532,256]^T  (fp32 out)
// R17 = R15 (persistent-B-in-regs, LDS-staged streaming-A, counted vmcnt)
// with 12 m-strips instead of 6: grid 504 ~= 2 blocks/CU so one block's
// store burst drains under the co-resident block's compute phase.
// __launch_bounds__(512,4) caps VGPR at 128 (working set ~105: breg 64 +
// a 8 + acc 16 + addressing). R16 lesson: never give the compiler a reason
// to rematerialize breg (a[2][8] direct-global blew pressure; VGPR=52 showed
// breg was reloaded per subtile -> 100us latency-bound).

#define M_DIM 4096
#define K_DIM 256
#define N_LUT 5532
#define N_Q   5000
#define N_DIM (N_LUT + N_Q)   // 10532
#define BN    256
#define NT_N  42              // ceil(10532/256)
#define N_PAD (NT_N * 256)    // 10752
#define NSTRIP 12             // 128 subtiles: strips 0..7 have 11, 8..11 have 10

typedef _Float16 f16x8 __attribute__((ext_vector_type(8)));
typedef float f32x4 __attribute__((ext_vector_type(4)));

__device__ __forceinline__ unsigned short f2h(float f) {
  union { _Float16 h; unsigned short u; } v;
  v.h = (_Float16)f;   // v_cvt_f16_f32, RNE
  return v.u;
}

// ---------------- convert fp32 -> f16 into workspace ----------------
__global__ __launch_bounds__(256) void convert_kernel(
    const float* __restrict__ inp, const float* __restrict__ lut,
    const float* __restrict__ que, unsigned short* __restrict__ Abf,
    unsigned short* __restrict__ Bbf) {
  const int AV = M_DIM * K_DIM / 4;  // 262144 float4s for A
  int i = blockIdx.x * 256 + threadIdx.x;  // grid sized exactly
  float4 x;
  unsigned short* dst;
  if (i < AV) {
    x = ((const float4*)inp)[i];
    dst = Abf + i * 4;
  } else {
    int e = (i - AV) * 4;          // element index in padded B
    int row = e >> 8;              // /256
    int col = e & 255;
    if (row < N_LUT)
      x = *(const float4*)(lut + (size_t)row * K_DIM + col);
    else if (row < N_DIM)
      x = *(const float4*)(que + (size_t)(row - N_LUT) * K_DIM + col);
    else
      x = make_float4(0.f, 0.f, 0.f, 0.f);
    dst = Bbf + e;
  }
  ushort4 o;
  o.x = f2h(x.x); o.y = f2h(x.y); o.z = f2h(x.z); o.w = f2h(x.w);
  *(ushort4*)dst = o;
}

// ---------------- GEMM: persistent-B-in-regs, streaming-A ----------------
#define GLDS16(gsrc, ldst)                                                  \
  __builtin_amdgcn_global_load_lds(                                         \
      (__attribute__((address_space(1))) void*)(gsrc),                      \
      (__attribute__((address_space(3))) void*)(ldst), 16, 0, 0)

__global__ __launch_bounds__(512, 4) void gemm_kernel(
    const unsigned short* __restrict__ A, const unsigned short* __restrict__ B,
    float* __restrict__ C) {
  // A only: double-buffered 32 rows x 256 k = 2 x 16 KiB (B lives in VGPRs)
  __shared__ __align__(16) unsigned short As[2][32 * 256];

  const int t = threadIdx.x;
  const int lane = t & 63;
  const int wave = t >> 6;         // 8 waves; wave w owns C-cols w*32..+32

  const int bid = blockIdx.x;      // 504 blocks: bn fast, strip slow
  const int bn = bid % NT_N;
  const int s = bid / NT_N;        // strip 0..11
  const int bcol = bn * BN;
  const bool fullN = (bcol + BN <= N_DIM);  // false only for bn==41
  // strips: 0..7 -> 11 subtiles, 8..11 -> 10 (8*11 + 4*10 = 128)
  const int csub = (s < 8) ? 11 : 10;
  const int sub0 = (s < 8) ? s * 11 : 88 + (s - 8) * 10;
  const int row0 = sub0 * 32;

  const int lr = lane & 15;
  const int rsw = lane & 7;        // = row&7 for all fragment rows
  const int cq = lane >> 4;        // 0..3
  const int cc4 = cq * 4;

  // ---- persistent B fragments -> registers (64 VGPR) ----
  // breg[j][ks]: B-row = bcol + wave*32 + j*16 + lr, k = ks*32 + cq*8.
  // Bbf padded/zeroed to N_PAD rows -> bn==41 loads in-bounds.
  f16x8 breg[2][8];
#pragma unroll
  for (int j = 0; j < 2; ++j) {
    const unsigned short* brow =
        B + (size_t)(bcol + wave * 32 + j * 16 + lr) * K_DIM + cq * 8;
#pragma unroll
    for (int ks = 0; ks < 8; ++ks)
      breg[j][ks] = *(const f16x8*)(brow + ks * 32);
  }

  // ---- A staging geometry (rows of 256 f16 = 32 x 16B chunks) ----
  // swizzle: lds[row][c] = global[row][c ^ (row&7)]; staging thread t in
  // round r covers slot row = r*16 + (t>>5), chunk = t&31 -> fetch swizzled.
  const int srow = t >> 5;                        // 0..15 within round
  const int scs = (((t & 31) ^ (srow & 7)) * 8);  // swizzled col, elements
  const unsigned short* gaBase0 = A + (size_t)(row0 + srow) * K_DIM + scs;
  const int ldsRound = wave * 2 * 256;  // wave-uniform base per round (elems)

  // A subtile: 32 rows = 2 rounds of 16 (2 gload_lds per thread)
#define STAGE_A(buf, sub)                                                    \
  do {                                                                       \
    _Pragma("unroll") for (int r = 0; r < 2; ++r)                            \
      GLDS16(gaBase0 + ((size_t)(sub) * 32 + r * 16) * K_DIM,                \
             As[buf] + r * 16 * 256 + ldsRound);                             \
  } while (0)

  STAGE_A(0, 0);
  __syncthreads();                 // full drain + barrier (once)

  int cur = 0;
#pragma unroll 1
  for (int sub = 0; sub < csub; ++sub) {
    if (sub + 1 < csub)
      STAGE_A(cur ^ 1, sub + 1);   // 2 gload_lds: oldest in vmem queue
    __builtin_amdgcn_sched_barrier(0);  // pin loads ABOVE compute+stores

    f32x4 acc[2][2] = {};
#pragma unroll
    for (int ks = 0; ks < 8; ++ks) {           // K = 256 = 8 x 32
      const int ch = (ks * 4 + cq) ^ rsw;      // swizzled 16B chunk, 0..31
      f16x8 a[2];
#pragma unroll
      for (int i = 0; i < 2; ++i)
        a[i] = *(const f16x8*)&As[cur][(i * 16 + lr) * 256 + ch * 8];
      // swapped operands: C-row = i*16+lr, C-cols = j*16 + cc4 + reg
#pragma unroll
      for (int i = 0; i < 2; ++i)
#pragma unroll
        for (int j = 0; j < 2; ++j)
          acc[i][j] = __builtin_amdgcn_mfma_f32_16x16x32_f16(breg[j][ks], a[i],
                                                             acc[i][j], 0, 0, 0);
    }

    // 4 dwordx4 C-stores (newest in vmem queue; ride across the barrier)
#pragma unroll
    for (int i = 0; i < 2; ++i) {
      size_t rowBase = (size_t)(row0 + sub * 32 + i * 16 + lr) * N_DIM;
#pragma unroll
      for (int j = 0; j < 2; ++j) {
        int col = bcol + wave * 32 + j * 16 + cc4;
        if (col < N_DIM)           // N_DIM%4==0: granule fully valid
          *(f32x4*)&C[rowBase + col] = acc[i][j];
      }
    }

    if (sub + 1 < csub) {
      // counted wait: A(next) loads (older) complete; this subtile's 4
      // stores stay in flight and drain under next compute. vmcnt BEFORE
      // barrier (R2 race lesson). bn==41: store instr count varies -> 0.
      if (fullN)
        asm volatile("s_waitcnt vmcnt(4)" ::: "memory");
      else
        asm volatile("s_waitcnt vmcnt(0)" ::: "memory");
      asm volatile("s_barrier" ::: "memory");
    }
    cur ^= 1;
  }
#undef STAGE_A
}

extern "C" void kernel_launch(void* const* d_in, const int* in_sizes, int n_in,
                              void* d_out, int out_size, void* d_ws, size_t ws_size,
                              hipStream_t stream) {
  const float* inp = (const float*)d_in[0];   // inputs [4096,256]
  // d_in[1] targets, d_in[2] gt_flag: unused by the forward similarity
  const float* lut = (const float*)d_in[3];   // [5532,256]
  const float* que = (const float*)d_in[4];   // [5000,256]
  float* C = (float*)d_out;                   // [4096,10532]

  unsigned short* Abf = (unsigned short*)d_ws;
  unsigned short* Bbf = Abf + (size_t)M_DIM * K_DIM;  // ~7.7 MB of ws

  const int conv_blocks = (M_DIM * K_DIM / 4 + N_PAD * K_DIM / 4) / 256;
  convert_kernel<<<conv_blocks, 256, 0, stream>>>(inp, lut, que, Abf, Bbf);

  gemm_kernel<<<NSTRIP * NT_N, 512, 0, stream>>>(Abf, Bbf, C);
}

// Round 18
// 47.511 us; speedup vs baseline: 2.2430x; 1.0736x over previous
//
#include <hip/hip_runtime.h>
#include <hip/hip_bf16.h>
#include <stdint.h>

// C[4096,10532] = inputs[4096,256] @ concat(lut,queue)[10532,256]^T  (fp32 out)
// R18 = R15 (persistent-B-in-regs, LDS-staged streaming-A, counted vmcnt,
// 252 blocks, (512,2)) + ONE change: bijective XCD-chunked block swizzle
// (m204 form). C rows start at 16 mod 128, so every bn-boundary 128-B line is
// half-written by two blocks; without the swizzle those two blocks sit on
// DIFFERENT XCDs (hw round-robin bid%8) -> two partial writebacks -> HBM
// controller RMW -> measured ~4.1 TB/s effective write drain. Chunked swizzle
// puts contiguous (strip,bn) runs on one XCD so boundary lines merge in its
// L2 before writeback. R17 lesson: keep 6 strips / 1 block/CU (2/CU lost).

#define M_DIM 4096
#define K_DIM 256
#define N_LUT 5532
#define N_Q   5000
#define N_DIM (N_LUT + N_Q)   // 10532
#define BN    256
#define NT_N  42              // ceil(10532/256)
#define N_PAD (NT_N * 256)    // 10752
#define NSTRIP 6              // m-strips; 128 subtiles of 32 rows split 21/22

typedef _Float16 f16x8 __attribute__((ext_vector_type(8)));
typedef float f32x4 __attribute__((ext_vector_type(4)));

__device__ __forceinline__ unsigned short f2h(float f) {
  union { _Float16 h; unsigned short u; } v;
  v.h = (_Float16)f;   // v_cvt_f16_f32, RNE
  return v.u;
}

// ---------------- convert fp32 -> f16 into workspace ----------------
__global__ __launch_bounds__(256) void convert_kernel(
    const float* __restrict__ inp, const float* __restrict__ lut,
    const float* __restrict__ que, unsigned short* __restrict__ Abf,
    unsigned short* __restrict__ Bbf) {
  const int AV = M_DIM * K_DIM / 4;  // 262144 float4s for A
  int i = blockIdx.x * 256 + threadIdx.x;  // grid sized exactly
  float4 x;
  unsigned short* dst;
  if (i < AV) {
    x = ((const float4*)inp)[i];
    dst = Abf + i * 4;
  } else {
    int e = (i - AV) * 4;          // element index in padded B
    int row = e >> 8;              // /256
    int col = e & 255;
    if (row < N_LUT)
      x = *(const float4*)(lut + (size_t)row * K_DIM + col);
    else if (row < N_DIM)
      x = *(const float4*)(que + (size_t)(row - N_LUT) * K_DIM + col);
    else
      x = make_float4(0.f, 0.f, 0.f, 0.f);
    dst = Bbf + e;
  }
  ushort4 o;
  o.x = f2h(x.x); o.y = f2h(x.y); o.z = f2h(x.z); o.w = f2h(x.w);
  *(ushort4*)dst = o;
}

// ---------------- GEMM: persistent-B-in-regs, streaming-A ----------------
#define GLDS16(gsrc, ldst)                                                  \
  __builtin_amdgcn_global_load_lds(                                         \
      (__attribute__((address_space(1))) void*)(gsrc),                      \
      (__attribute__((address_space(3))) void*)(ldst), 16, 0, 0)

__global__ __launch_bounds__(512, 2) void gemm_kernel(
    const unsigned short* __restrict__ A, const unsigned short* __restrict__ B,
    float* __restrict__ C) {
  // A only: double-buffered 32 rows x 256 k = 2 x 16 KiB (B lives in VGPRs)
  __shared__ __align__(16) unsigned short As[2][32 * 256];

  const int t = threadIdx.x;
  const int lane = t & 63;
  const int wave = t >> 6;         // 8 waves; wave w owns C-cols w*32..+32

  // ---- bijective XCD-chunked swizzle (m204): nwg=252, q=31, r=4 ----
  // hw XCD = bid%8; XCD x owns a CONTIGUOUS logical range, logical order is
  // bn-fast within strip -> bn-adjacent blocks share one L2 (boundary-line
  // merge before HBM writeback).
  {
  }
  const int bid = blockIdx.x;
  const int xcd = bid & 7, idx = bid >> 3;       // q=31, r=4 hard-coded
  const int wg =
      ((xcd < 4) ? xcd * 32 : 128 + (xcd - 4) * 31) + idx;
  const int s = wg / NT_N;         // strip 0..5
  const int bn = wg % NT_N;        // bn-fast within strip
  const int bcol = bn * BN;
  const bool fullN = (bcol + BN <= N_DIM);  // false only for bn==41
  // strips: subtile counts 21,21,21,21,22,22 (sum 128)
  const int csub = 21 + (s >= 4 ? 1 : 0);
  const int sub0 = 21 * s + (s >= 5 ? 1 : 0);   // s=5 starts at 106
  const int row0 = sub0 * 32;

  const int lr = lane & 15;
  const int rsw = lane & 7;        // = row&7 for all fragment rows
  const int cq = lane >> 4;        // 0..3
  const int cc4 = cq * 4;

  // ---- persistent B fragments -> registers (64 VGPR) ----
  // breg[j][ks]: B-row = bcol + wave*32 + j*16 + lr, k = ks*32 + cq*8.
  // Bbf padded/zeroed to N_PAD rows -> bn==41 loads in-bounds.
  f16x8 breg[2][8];
#pragma unroll
  for (int j = 0; j < 2; ++j) {
    const unsigned short* brow =
        B + (size_t)(bcol + wave * 32 + j * 16 + lr) * K_DIM + cq * 8;
#pragma unroll
    for (int ks = 0; ks < 8; ++ks)
      breg[j][ks] = *(const f16x8*)(brow + ks * 32);
  }

  // ---- A staging geometry (rows of 256 f16 = 32 x 16B chunks) ----
  // swizzle: lds[row][c] = global[row][c ^ (row&7)]; staging thread t in
  // round r covers slot row = r*16 + (t>>5), chunk = t&31 -> fetch swizzled.
  const int srow = t >> 5;                        // 0..15 within round
  const int scs = (((t & 31) ^ (srow & 7)) * 8);  // swizzled col, elements
  const unsigned short* gaBase0 = A + (size_t)(row0 + srow) * K_DIM + scs;
  const int ldsRound = wave * 2 * 256;  // wave-uniform base per round (elems)

  // A subtile: 32 rows = 2 rounds of 16 (2 gload_lds per thread)
#define STAGE_A(buf, sub)                                                    \
  do {                                                                       \
    _Pragma("unroll") for (int r = 0; r < 2; ++r)                            \
      GLDS16(gaBase0 + ((size_t)(sub) * 32 + r * 16) * K_DIM,                \
             As[buf] + r * 16 * 256 + ldsRound);                             \
  } while (0)

  STAGE_A(0, 0);
  __syncthreads();                 // full drain + barrier (once)

  int cur = 0;
#pragma unroll 1
  for (int sub = 0; sub < csub; ++sub) {
    if (sub + 1 < csub)
      STAGE_A(cur ^ 1, sub + 1);   // 2 gload_lds: oldest in vmem queue
    __builtin_amdgcn_sched_barrier(0);  // pin loads ABOVE compute+stores

    f32x4 acc[2][2] = {};
#pragma unroll
    for (int ks = 0; ks < 8; ++ks) {           // K = 256 = 8 x 32
      const int ch = (ks * 4 + cq) ^ rsw;      // swizzled 16B chunk, 0..31
      f16x8 a[2];
#pragma unroll
      for (int i = 0; i < 2; ++i)
        a[i] = *(const f16x8*)&As[cur][(i * 16 + lr) * 256 + ch * 8];
      // swapped operands: C-row = i*16+lr, C-cols = j*16 + cc4 + reg
#pragma unroll
      for (int i = 0; i < 2; ++i)
#pragma unroll
        for (int j = 0; j < 2; ++j)
          acc[i][j] = __builtin_amdgcn_mfma_f32_16x16x32_f16(breg[j][ks], a[i],
                                                             acc[i][j], 0, 0, 0);
    }

    // 4 dwordx4 C-stores (newest in vmem queue; ride across the barrier)
#pragma unroll
    for (int i = 0; i < 2; ++i) {
      size_t rowBase = (size_t)(row0 + sub * 32 + i * 16 + lr) * N_DIM;
#pragma unroll
      for (int j = 0; j < 2; ++j) {
        int col = bcol + wave * 32 + j * 16 + cc4;
        if (col < N_DIM)           // N_DIM%4==0: granule fully valid
          *(f32x4*)&C[rowBase + col] = acc[i][j];
      }
    }

    if (sub + 1 < csub) {
      // counted wait: A(next) loads (older) complete; this subtile's 4
      // stores stay in flight and drain under next compute. vmcnt BEFORE
      // barrier (R2 race lesson). bn==41: store instr count varies -> 0.
      if (fullN)
        asm volatile("s_waitcnt vmcnt(4)" ::: "memory");
      else
        asm volatile("s_waitcnt vmcnt(0)" ::: "memory");
      asm volatile("s_barrier" ::: "memory");
    }
    cur ^= 1;
  }
#undef STAGE_A
}

extern "C" void kernel_launch(void* const* d_in, const int* in_sizes, int n_in,
                              void* d_out, int out_size, void* d_ws, size_t ws_size,
                              hipStream_t stream) {
  const float* inp = (const float*)d_in[0];   // inputs [4096,256]
  // d_in[1] targets, d_in[2] gt_flag: unused by the forward similarity
  const float* lut = (const float*)d_in[3];   // [5532,256]
  const float* que = (const float*)d_in[4];   // [5000,256]
  float* C = (float*)d_out;                   // [4096,10532]

  unsigned short* Abf = (unsigned short*)d_ws;
  unsigned short* Bbf = Abf + (size_t)M_DIM * K_DIM;  // ~7.7 MB of ws

  const int conv_blocks = (M_DIM * K_DIM / 4 + N_PAD * K_DIM / 4) / 256;
  convert_kernel<<<conv_blocks, 256, 0, stream>>>(inp, lut, que, Abf, Bbf);

  gemm_kernel<<<NSTRIP * NT_N, 512, 0, stream>>>(Abf, Bbf, C);
}